// Round 4
// baseline (227.236 us; speedup 1.0000x reference)
//
#include <hip/hip_runtime.h>

// Problem constants (from reference)
#define HH 4096
#define WW 4096
#define NB 1024
#define NCHUNK 64
#define CROWS 64          // HH / NCHUNK
#define IOU_T 0.5f

typedef unsigned long long u64;

// ---------------- workspace layout ------------------------------------------
constexpr size_t OFF_COORDS = 0;                                   // int4 x NB (16 KB)
constexpr size_t OFF_RD     = OFF_COORDS + (size_t)NB * 16;        // int4 x HH (64 KB)
constexpr size_t OFF_PART   = OFF_RD     + (size_t)HH * 16;        // double x NCHUNK*WW (2 MB)
constexpr size_t OFF_SC64   = OFF_PART   + (size_t)NCHUNK * WW * 8;// double x NB
constexpr size_t OFF_BS     = OFF_SC64   + (size_t)NB * 8;         // float4 x NB
constexpr size_t OFF_SSD    = OFF_BS     + (size_t)NB * 16;        // double x NB
constexpr size_t OFF_IOU    = OFF_SSD    + (size_t)NB * 8;         // u64 x NB*16 (128 KB)
constexpr size_t OFF_CC     = OFF_IOU    + (size_t)NB * 16 * 8;    // float x 2048*WW (32 MB)
// total ~= 34.3 MB

// ---------------- kernels ---------------------------------------------------

// merged: box coords + row flags + exclusive scan + per-row x-range union.
// rowdesc[r] = { slot or -1, p0 (first col-pair), p1 (end col-pair), 0 }
__global__ void k_setup(const float* __restrict__ bbox, int4* coords,
                        int4* rowdesc) {
    __shared__ int lf[HH];        // 16 KB
    __shared__ int xlo[HH];       // 16 KB
    __shared__ int xhi[HH];       // 16 KB
    __shared__ int psum[256];
    int t = threadIdx.x;
    for (int k = t; k < HH; k += 256) { lf[k] = 0; xlo[k] = WW; xhi[k] = 0; }
    __syncthreads();
    for (int i = t; i < NB; i += 256) {
        float b0 = bbox[i * 4 + 0], b1 = bbox[i * 4 + 1];
        float b2 = bbox[i * 4 + 2], b3 = bbox[i * 4 + 3];
        int x1 = min(max((int)floorf(b0), 0), WW);
        int y1 = min(max((int)floorf(b1), 0), HH);
        int x2 = min(max((int)floorf(b2), 0), WW);
        int y2 = min(max((int)floorf(b3), 0), HH);
        coords[i] = make_int4(x1, y1, x2, y2);
        if (y1 >= 1) {
            lf[y1 - 1] = 1;                      // benign races: same value
            atomicMin(&xlo[y1 - 1], x1);
            atomicMax(&xhi[y1 - 1], x2);
        }
        if (y2 >= 1) {
            lf[y2 - 1] = 1;
            atomicMin(&xlo[y2 - 1], x1);
            atomicMax(&xhi[y2 - 1], x2);
        }
    }
    __syncthreads();
    int base = t * 16;
    int s = 0;
    for (int k = 0; k < 16; k++) s += lf[base + k];
    psum[t] = s;
    __syncthreads();
    if (t == 0) {
        int acc = 0;
        for (int k = 0; k < 256; k++) { int v = psum[k]; psum[k] = acc; acc += v; }
    }
    __syncthreads();
    int run = psum[t];
    for (int k = 0; k < 16; k++) {
        int r = base + k;
        int fl = lf[r];
        rowdesc[r] = make_int4(fl ? run : -1, xlo[r] >> 1, (xhi[r] + 1) >> 1, 0);
        run += fl;
    }
}

// fused staging: ONE read of probs. fp64 within-chunk column cumsum; emit fp32
// cumsum rows at flagged rows (only needed column segment); chunk totals ->
// part (fp64). float2 loads + 8-row unroll for latency coverage.
__global__ void __launch_bounds__(256) k_stage(const float* __restrict__ probs,
        const int4* __restrict__ rowdesc,
        double* __restrict__ part, float* __restrict__ Cc) {
    int tid = blockIdx.x * 256 + threadIdx.x;   // NCHUNK * WW/2 threads
    int c  = tid >> 11;          // chunk (WW/2 == 2048 col-pairs)
    int xg = tid & 2047;         // col-pair index
    const float2* p = (const float2*)probs + (size_t)c * CROWS * (WW / 2) + xg;
    const int4* rd = rowdesc + c * CROWS;
    float2* Cc2 = (float2*)Cc;
    double a0 = 0.0, a1 = 0.0;
    for (int r = 0; r < CROWS; r += 8) {
        float2 q[8];
        #pragma unroll
        for (int k = 0; k < 8; k++) q[k] = p[(size_t)(r + k) * (WW / 2)];
        #pragma unroll
        for (int k = 0; k < 8; k++) {
            a0 += (double)q[k].x; a1 += (double)q[k].y;
            int4 d = rd[r + k];
            if (d.x >= 0 && xg >= d.y && xg < d.z)
                Cc2[(size_t)d.x * (WW / 2) + xg] = make_float2((float)a0, (float)a1);
        }
    }
    ((double2*)part)[(size_t)c * (WW / 2) + xg] = make_double2(a0, a1);
}

// in-place exclusive scan of part along chunk axis (per column), grouped loads
__global__ void k_chunkscan(double* __restrict__ part) {
    int x = blockIdx.x * blockDim.x + threadIdx.x;   // WW threads
    double carry = 0.0;
    for (int g = 0; g < NCHUNK / 16; g++) {
        double v[16];
        #pragma unroll
        for (int k = 0; k < 16; k++) v[k] = part[(size_t)(g * 16 + k) * WW + x];
        #pragma unroll
        for (int k = 0; k < 16; k++) { double tv = v[k]; v[k] = carry; carry += tv; }
        #pragma unroll
        for (int k = 0; k < 16; k++) part[(size_t)(g * 16 + k) * WW + x] = v[k];
    }
}

// per-box rectangle sum: one wave per box; column value = within-chunk fp32
// cumsum row + fp64 chunk prefix. fp64 shuffle-reduce.
__global__ void __launch_bounds__(64) k_boxsum(const int4* __restrict__ coords,
                         const float* __restrict__ obj,
                         const int4* __restrict__ rowdesc, const float* __restrict__ Cc,
                         const double* __restrict__ part,
                         double* sc64) {
    int i = blockIdx.x;
    int lane = threadIdx.x;
    int4 cd = coords[i]; // x=x1, y=y1, z=x2, w=y2
    bool h1 = (cd.y >= 1), h2 = (cd.w >= 1);
    int s1 = h1 ? rowdesc[cd.y - 1].x : 0;
    int s2 = h2 ? rowdesc[cd.w - 1].x : 0;
    const float*  r2 = Cc   + (size_t)(h2 ? s2 : 0) * WW;
    const double* q2 = part + (size_t)(h2 ? ((cd.w - 1) >> 6) : 0) * WW;
    const float*  r1 = Cc   + (size_t)(h1 ? s1 : 0) * WW;
    const double* q1 = part + (size_t)(h1 ? ((cd.y - 1) >> 6) : 0) * WW;
    double s = 0.0;
    for (int x = cd.x + lane; x < cd.z; x += 64) {
        double v2 = h2 ? ((double)r2[x] + q2[x]) : 0.0;
        double v1 = h1 ? ((double)r1[x] + q1[x]) : 0.0;
        s += (v2 - v1);
    }
    #pragma unroll
    for (int off = 32; off > 0; off >>= 1) s += __shfl_down(s, off);
    if (lane == 0) {
        long long cnt = (long long)(cd.w - cd.y) * (long long)(cd.z - cd.x);
        if (cnt < 1) cnt = 1;
        double box = s / (double)cnt;
        sc64[i] = 0.5 * ((double)obj[i] + box);
    }
}

// stable descending rank sort + gather, single block (order stays in LDS).
// rank = #{j : s_j > s_i or (s_j == s_i and j < i)}
__global__ void __launch_bounds__(1024) k_rankgather(const double* __restrict__ sc64,
                        const float* __restrict__ bbox,
                        float4* bs, double* ssd) {
    __shared__ double s[NB];
    __shared__ int order[NB];
    int t = threadIdx.x;   // 1024 threads == NB
    s[t] = sc64[t];
    __syncthreads();
    double si = s[t];
    int rank = 0;
    for (int j = 0; j < NB; j++) {
        double sj = s[j];
        rank += (sj > si) || (sj == si && j < t);
    }
    order[rank] = t;
    __syncthreads();
    int o = order[t];
    bs[t] = ((const float4*)bbox)[o];
    ssd[t] = s[o];
}

// IoU(bs_i, bs_j) > 0.5 bit matrix, one u64 word per 64 j's via ballot
__global__ void k_iou(const float4* __restrict__ bs, u64* __restrict__ ioub) {
    int tid = blockIdx.x * blockDim.x + threadIdx.x; // NB*NB threads
    int i = tid >> 10;
    int j = tid & (NB - 1);
    float4 a = bs[i], b = bs[j];
    float ai = (a.z - a.x) * (a.w - a.y);
    float aj = (b.z - b.x) * (b.w - b.y);
    float ix1 = fmaxf(a.x, b.x), iy1 = fmaxf(a.y, b.y);
    float ix2 = fminf(a.z, b.z), iy2 = fminf(a.w, b.w);
    float iw = fmaxf(ix2 - ix1, 0.0f), ih = fmaxf(iy2 - iy1, 0.0f);
    float inter = iw * ih;
    float iou_v = inter / (ai + aj - inter);
    bool bit = iou_v > IOU_T;
    u64 m = __ballot(bit);
    if ((threadIdx.x & 63) == 0) ioub[(size_t)i * 16 + (j >> 6)] = m;
}

// greedy grouping + final reduction fused, one block of NB threads.
// Masks in registers; statically-unrolled word loop + ctz scan walks the
// SAME increasing-j greedy order as the reference (inc updated per add).
// Record rule: group hits K via an add at j0 -> recorded at top of j0+1,
// i.e. rec iff size==K && last_add <= NB-2 (check-before-add semantics).
__global__ void __launch_bounds__(1024) k_groupfinal(const u64* __restrict__ ioub,
                        const double* __restrict__ ssd,
                        const int* __restrict__ counts,
                        float* __restrict__ out) {
    __shared__ double ssd_s[NB];   // 8 KB
    __shared__ double bsc[NB];     // 8 KB
    __shared__ int bidx[NB];       // 4 KB
    __shared__ u64 bestsel[16];
    __shared__ int best_s, any_s;
    int t = threadIdx.x;   // == start index i
    ssd_s[t] = ssd[t];
    __syncthreads();
    int K = counts[0];
    u64 inc[16], sel[16];
    int wi = t >> 6, bi = t & 63;
    #pragma unroll
    for (int w = 0; w < 16; w++) {
        inc[w] = ioub[(size_t)t * 16 + w];
        sel[w] = (w == wi) ? (1ULL << bi) : 0ULL;
    }
    int size = 1;
    double score = ssd_s[t];
    int last = t;
    #pragma unroll
    for (int w = 0; w < 16; w++) {
        if (w < wi || size >= K) continue;
        u64 avail = ~inc[w];
        if (w == wi) avail &= (bi == 63) ? 0ULL : (~0ULL << (bi + 1));
        while (avail != 0ULL && size < K) {
            int b = __builtin_ctzll(avail);
            int j = (w << 6) + b;
            sel[w] |= 1ULL << b;
            size++;
            score += ssd_s[j];
            last = j;
            const u64* rj = ioub + (size_t)j * 16;
            #pragma unroll
            for (int w2 = 0; w2 < 16; w2++) inc[w2] |= rj[w2];
            avail &= ~inc[w];          // diagonal bit of row j clears b too
            avail &= ~(1ULL << b);     // safety
        }
    }
    int rec = (size == K) && (last < NB - 1);
    bsc[t] = rec ? score : -1e300;
    bidx[t] = t;
    __syncthreads();
    for (int st = 512; st > 0; st >>= 1) {
        if (t < st) {
            double a = bsc[t], b2 = bsc[t + st];
            if (b2 > a || (b2 == a && bidx[t + st] > bidx[t])) {
                bsc[t] = b2;
                bidx[t] = bidx[t + st];
            }
        }
        __syncthreads();
    }
    if (t == 0) { best_s = bidx[0]; any_s = (bsc[0] > -1e299) ? 1 : 0; }
    __syncthreads();
    if (t == best_s) {
        #pragma unroll
        for (int w = 0; w < 16; w++) bestsel[w] = sel[w];
    }
    __syncthreads();
    float v = 0.0f;
    if (any_s && ((bestsel[t >> 6] >> (t & 63)) & 1ULL)) v = (float)ssd_s[t];
    out[t] = v;
}

// ---------------- host entry ------------------------------------------------

extern "C" void kernel_launch(void* const* d_in, const int* in_sizes, int n_in,
                              void* d_out, int out_size, void* d_ws, size_t ws_size,
                              hipStream_t stream) {
    const float* bbox  = (const float*)d_in[0];
    const float* obj   = (const float*)d_in[1];
    const float* probs = (const float*)d_in[2];
    const int*   counts = (const int*)d_in[3];
    float* out = (float*)d_out;

    char* w = (char*)d_ws;
    int4*   coords  = (int4*)(w + OFF_COORDS);
    int4*   rowdesc = (int4*)(w + OFF_RD);
    double* part    = (double*)(w + OFF_PART);
    double* sc64    = (double*)(w + OFF_SC64);
    float4* bs      = (float4*)(w + OFF_BS);
    double* ssd     = (double*)(w + OFF_SSD);
    u64*    ioub    = (u64*)(w + OFF_IOU);
    float*  Cc      = (float*)(w + OFF_CC);

    k_setup<<<1, 256, 0, stream>>>(bbox, coords, rowdesc);
    k_stage<<<(NCHUNK * WW / 2) / 256, 256, 0, stream>>>(probs, rowdesc, part, Cc);
    k_chunkscan<<<WW / 256, 256, 0, stream>>>(part);
    k_boxsum<<<NB, 64, 0, stream>>>(coords, obj, rowdesc, Cc, part, sc64);
    k_rankgather<<<1, 1024, 0, stream>>>(sc64, bbox, bs, ssd);
    k_iou<<<(NB * NB) / 256, 256, 0, stream>>>(bs, ioub);
    k_groupfinal<<<1, 1024, 0, stream>>>(ioub, ssd, counts, out);
}

// Round 5
// 199.278 us; speedup vs baseline: 1.1403x; 1.1403x over previous
//
#include <hip/hip_runtime.h>

// Problem constants (from reference)
#define HH 4096
#define WW 4096
#define NB 1024
#define NCHUNK 64
#define CROWS 64          // HH / NCHUNK
#define IOU_T 0.5f

typedef unsigned long long u64;

// ---------------- workspace layout ------------------------------------------
constexpr size_t OFF_COORDS = 0;                                   // int4 x NB (16 KB)
constexpr size_t OFF_RD     = OFF_COORDS + (size_t)NB * 16;        // int4 x HH (64 KB)
constexpr size_t OFF_PART   = OFF_RD     + (size_t)HH * 16;        // double x NCHUNK*WW (2 MB)
constexpr size_t OFF_SC64   = OFF_PART   + (size_t)NCHUNK * WW * 8;// double x NB
constexpr size_t OFF_BS     = OFF_SC64   + (size_t)NB * 8;         // float4 x NB
constexpr size_t OFF_SSD    = OFF_BS     + (size_t)NB * 16;        // double x NB
constexpr size_t OFF_IOU    = OFF_SSD    + (size_t)NB * 8;         // u64 x NB*16 (128 KB)
constexpr size_t OFF_RECSC  = OFF_IOU    + (size_t)NB * 16 * 8;    // double x NB
constexpr size_t OFF_RECSEL = OFF_RECSC  + (size_t)NB * 8;         // u64 x NB*16 (128 KB)
constexpr size_t OFF_CC     = OFF_RECSEL + (size_t)NB * 16 * 8;    // float x 2048*WW (32 MB)
// total ~= 34.4 MB

// ---------------- kernels ---------------------------------------------------

// merged: box coords + row flags + exclusive scan + per-row x-range union.
// rowdesc[r] = { slot or -1, p0 (first col-pair), p1 (end col-pair), 0 }
__global__ void k_setup(const float* __restrict__ bbox, int4* coords,
                        int4* rowdesc) {
    __shared__ int lf[HH];        // 16 KB
    __shared__ int xlo[HH];       // 16 KB
    __shared__ int xhi[HH];       // 16 KB
    __shared__ int psum[256];
    int t = threadIdx.x;
    for (int k = t; k < HH; k += 256) { lf[k] = 0; xlo[k] = WW; xhi[k] = 0; }
    __syncthreads();
    for (int i = t; i < NB; i += 256) {
        float b0 = bbox[i * 4 + 0], b1 = bbox[i * 4 + 1];
        float b2 = bbox[i * 4 + 2], b3 = bbox[i * 4 + 3];
        int x1 = min(max((int)floorf(b0), 0), WW);
        int y1 = min(max((int)floorf(b1), 0), HH);
        int x2 = min(max((int)floorf(b2), 0), WW);
        int y2 = min(max((int)floorf(b3), 0), HH);
        coords[i] = make_int4(x1, y1, x2, y2);
        if (y1 >= 1) {
            lf[y1 - 1] = 1;                      // benign races: same value
            atomicMin(&xlo[y1 - 1], x1);
            atomicMax(&xhi[y1 - 1], x2);
        }
        if (y2 >= 1) {
            lf[y2 - 1] = 1;
            atomicMin(&xlo[y2 - 1], x1);
            atomicMax(&xhi[y2 - 1], x2);
        }
    }
    __syncthreads();
    int base = t * 16;
    int s = 0;
    for (int k = 0; k < 16; k++) s += lf[base + k];
    psum[t] = s;
    __syncthreads();
    if (t == 0) {
        int acc = 0;
        for (int k = 0; k < 256; k++) { int v = psum[k]; psum[k] = acc; acc += v; }
    }
    __syncthreads();
    int run = psum[t];
    for (int k = 0; k < 16; k++) {
        int r = base + k;
        int fl = lf[r];
        rowdesc[r] = make_int4(fl ? run : -1, xlo[r] >> 1, (xhi[r] + 1) >> 1, 0);
        run += fl;
    }
}

// fused staging: ONE read of probs. fp64 within-chunk column cumsum; emit fp32
// cumsum rows at flagged rows (only needed column segment); chunk totals ->
// part (fp64). float2 loads + 8-row unroll for latency coverage.
__global__ void __launch_bounds__(256) k_stage(const float* __restrict__ probs,
        const int4* __restrict__ rowdesc,
        double* __restrict__ part, float* __restrict__ Cc) {
    int tid = blockIdx.x * 256 + threadIdx.x;   // NCHUNK * WW/2 threads
    int c  = tid >> 11;          // chunk (WW/2 == 2048 col-pairs)
    int xg = tid & 2047;         // col-pair index
    const float2* p = (const float2*)probs + (size_t)c * CROWS * (WW / 2) + xg;
    const int4* rd = rowdesc + c * CROWS;
    float2* Cc2 = (float2*)Cc;
    double a0 = 0.0, a1 = 0.0;
    for (int r = 0; r < CROWS; r += 8) {
        float2 q[8];
        #pragma unroll
        for (int k = 0; k < 8; k++) q[k] = p[(size_t)(r + k) * (WW / 2)];
        #pragma unroll
        for (int k = 0; k < 8; k++) {
            a0 += (double)q[k].x; a1 += (double)q[k].y;
            int4 d = rd[r + k];
            if (d.x >= 0 && xg >= d.y && xg < d.z)
                Cc2[(size_t)d.x * (WW / 2) + xg] = make_float2((float)a0, (float)a1);
        }
    }
    ((double2*)part)[(size_t)c * (WW / 2) + xg] = make_double2(a0, a1);
}

// in-place exclusive scan of part along chunk axis (per column), grouped loads
__global__ void k_chunkscan(double* __restrict__ part) {
    int x = blockIdx.x * blockDim.x + threadIdx.x;   // WW threads
    double carry = 0.0;
    for (int g = 0; g < NCHUNK / 16; g++) {
        double v[16];
        #pragma unroll
        for (int k = 0; k < 16; k++) v[k] = part[(size_t)(g * 16 + k) * WW + x];
        #pragma unroll
        for (int k = 0; k < 16; k++) { double tv = v[k]; v[k] = carry; carry += tv; }
        #pragma unroll
        for (int k = 0; k < 16; k++) part[(size_t)(g * 16 + k) * WW + x] = v[k];
    }
}

// per-box rectangle sum: one wave per box; column value = within-chunk fp32
// cumsum row + fp64 chunk prefix. fp64 shuffle-reduce.
__global__ void __launch_bounds__(64) k_boxsum(const int4* __restrict__ coords,
                         const float* __restrict__ obj,
                         const int4* __restrict__ rowdesc, const float* __restrict__ Cc,
                         const double* __restrict__ part,
                         double* sc64) {
    int i = blockIdx.x;
    int lane = threadIdx.x;
    int4 cd = coords[i]; // x=x1, y=y1, z=x2, w=y2
    bool h1 = (cd.y >= 1), h2 = (cd.w >= 1);
    int s1 = h1 ? rowdesc[cd.y - 1].x : 0;
    int s2 = h2 ? rowdesc[cd.w - 1].x : 0;
    const float*  r2 = Cc   + (size_t)(h2 ? s2 : 0) * WW;
    const double* q2 = part + (size_t)(h2 ? ((cd.w - 1) >> 6) : 0) * WW;
    const float*  r1 = Cc   + (size_t)(h1 ? s1 : 0) * WW;
    const double* q1 = part + (size_t)(h1 ? ((cd.y - 1) >> 6) : 0) * WW;
    double s = 0.0;
    for (int x = cd.x + lane; x < cd.z; x += 64) {
        double v2 = h2 ? ((double)r2[x] + q2[x]) : 0.0;
        double v1 = h1 ? ((double)r1[x] + q1[x]) : 0.0;
        s += (v2 - v1);
    }
    #pragma unroll
    for (int off = 32; off > 0; off >>= 1) s += __shfl_down(s, off);
    if (lane == 0) {
        long long cnt = (long long)(cd.w - cd.y) * (long long)(cd.z - cd.x);
        if (cnt < 1) cnt = 1;
        double box = s / (double)cnt;
        sc64[i] = 0.5 * ((double)obj[i] + box);
    }
}

// stable descending rank sort + gather, single block (order stays in LDS).
__global__ void __launch_bounds__(1024) k_rankgather(const double* __restrict__ sc64,
                        const float* __restrict__ bbox,
                        float4* bs, double* ssd) {
    __shared__ double s[NB];
    __shared__ int order[NB];
    int t = threadIdx.x;   // 1024 threads == NB
    s[t] = sc64[t];
    __syncthreads();
    double si = s[t];
    int rank = 0;
    for (int j = 0; j < NB; j++) {
        double sj = s[j];
        rank += (sj > si) || (sj == si && j < t);
    }
    order[rank] = t;
    __syncthreads();
    int o = order[t];
    bs[t] = ((const float4*)bbox)[o];
    ssd[t] = s[o];
}

// IoU(bs_i, bs_j) > 0.5 bit matrix, one u64 word per 64 j's via ballot
__global__ void k_iou(const float4* __restrict__ bs, u64* __restrict__ ioub) {
    int tid = blockIdx.x * blockDim.x + threadIdx.x; // NB*NB threads
    int i = tid >> 10;
    int j = tid & (NB - 1);
    float4 a = bs[i], b = bs[j];
    float ai = (a.z - a.x) * (a.w - a.y);
    float aj = (b.z - b.x) * (b.w - b.y);
    float ix1 = fmaxf(a.x, b.x), iy1 = fmaxf(a.y, b.y);
    float ix2 = fminf(a.z, b.z), iy2 = fminf(a.w, b.w);
    float iw = fmaxf(ix2 - ix1, 0.0f), ih = fmaxf(iy2 - iy1, 0.0f);
    float inter = iw * ih;
    float iou_v = inter / (ai + aj - inter);
    bool bit = iou_v > IOU_T;
    u64 m = __ballot(bit);
    if ((threadIdx.x & 63) == 0) ioub[(size_t)i * 16 + (j >> 6)] = m;
}

// greedy grouping, one thread per start, 16 blocks x 64 threads (16 CUs —
// R4's single-block fusion serialized this on 1 CU and cost 49 us).
// Register masks + ctz scan walk the SAME increasing-j greedy order as the
// reference (inc updated per add). Record rule: rec iff size==K and the
// last add happened at j <= NB-2 (check-before-add semantics).
__global__ void __launch_bounds__(64) k_group(const u64* __restrict__ ioub,
                        const double* __restrict__ ssd,
                        const int* __restrict__ counts,
                        double* __restrict__ recsc,
                        u64* __restrict__ recsel) {
    __shared__ double ssd_s[NB];   // 8 KB
    int t = threadIdx.x;
    int i = blockIdx.x * 64 + t;   // start index
    for (int k = t; k < NB; k += 64) ssd_s[k] = ssd[k];
    __syncthreads();
    int K = counts[0];
    u64 inc[16], sel[16];
    int wi = i >> 6, bi = i & 63;
    #pragma unroll
    for (int w = 0; w < 16; w++) {
        inc[w] = ioub[(size_t)i * 16 + w];
        sel[w] = (w == wi) ? (1ULL << bi) : 0ULL;
    }
    int size = 1;
    double score = ssd_s[i];
    int last = i;
    #pragma unroll
    for (int w = 0; w < 16; w++) {
        if (w < wi || size >= K) continue;
        u64 avail = ~inc[w];
        if (w == wi) avail &= (bi == 63) ? 0ULL : (~0ULL << (bi + 1));
        while (avail != 0ULL && size < K) {
            int b = __builtin_ctzll(avail);
            int j = (w << 6) + b;
            sel[w] |= 1ULL << b;
            size++;
            score += ssd_s[j];
            last = j;
            const u64* rj = ioub + (size_t)j * 16;
            #pragma unroll
            for (int w2 = 0; w2 < 16; w2++) inc[w2] |= rj[w2];
            avail &= ~inc[w];          // row j's own bits clear b et al.
            avail &= ~(1ULL << b);     // safety
        }
    }
    int rec = (size == K) && (last < NB - 1);
    recsc[i] = rec ? score : -1e300;
    #pragma unroll
    for (int w = 0; w < 16; w++) recsel[(size_t)i * 16 + w] = sel[w];
}

// best = max recorded score, ties -> LAST index (reference's last-argmax rule)
__global__ void __launch_bounds__(1024) k_final(const double* __restrict__ recsc,
                        const u64* __restrict__ recsel,
                        const double* __restrict__ ssd, float* __restrict__ out) {
    __shared__ double bsc[NB];
    __shared__ int bidx[NB];
    __shared__ int best_s, any_s;
    int t = threadIdx.x; // 1024 threads
    bsc[t] = recsc[t];
    bidx[t] = t;
    __syncthreads();
    for (int st = 512; st > 0; st >>= 1) {
        if (t < st) {
            double a = bsc[t], b2 = bsc[t + st];
            if (b2 > a || (b2 == a && bidx[t + st] > bidx[t])) {
                bsc[t] = b2;
                bidx[t] = bidx[t + st];
            }
        }
        __syncthreads();
    }
    if (t == 0) { best_s = bidx[0]; any_s = (bsc[0] > -1e299) ? 1 : 0; }
    __syncthreads();
    float v = 0.0f;
    if (any_s && ((recsel[(size_t)best_s * 16 + (t >> 6)] >> (t & 63)) & 1ULL))
        v = (float)ssd[t];
    out[t] = v;
}

// ---------------- host entry ------------------------------------------------

extern "C" void kernel_launch(void* const* d_in, const int* in_sizes, int n_in,
                              void* d_out, int out_size, void* d_ws, size_t ws_size,
                              hipStream_t stream) {
    const float* bbox  = (const float*)d_in[0];
    const float* obj   = (const float*)d_in[1];
    const float* probs = (const float*)d_in[2];
    const int*   counts = (const int*)d_in[3];
    float* out = (float*)d_out;

    char* w = (char*)d_ws;
    int4*   coords  = (int4*)(w + OFF_COORDS);
    int4*   rowdesc = (int4*)(w + OFF_RD);
    double* part    = (double*)(w + OFF_PART);
    double* sc64    = (double*)(w + OFF_SC64);
    float4* bs      = (float4*)(w + OFF_BS);
    double* ssd     = (double*)(w + OFF_SSD);
    u64*    ioub    = (u64*)(w + OFF_IOU);
    double* recsc   = (double*)(w + OFF_RECSC);
    u64*    recsel  = (u64*)(w + OFF_RECSEL);
    float*  Cc      = (float*)(w + OFF_CC);

    k_setup<<<1, 256, 0, stream>>>(bbox, coords, rowdesc);
    k_stage<<<(NCHUNK * WW / 2) / 256, 256, 0, stream>>>(probs, rowdesc, part, Cc);
    k_chunkscan<<<WW / 256, 256, 0, stream>>>(part);
    k_boxsum<<<NB, 64, 0, stream>>>(coords, obj, rowdesc, Cc, part, sc64);
    k_rankgather<<<1, 1024, 0, stream>>>(sc64, bbox, bs, ssd);
    k_iou<<<(NB * NB) / 256, 256, 0, stream>>>(bs, ioub);
    k_group<<<NB / 64, 64, 0, stream>>>(ioub, ssd, counts, recsc, recsel);
    k_final<<<1, 1024, 0, stream>>>(recsc, recsel, ssd, out);
}

// Round 6
// 188.622 us; speedup vs baseline: 1.2047x; 1.0565x over previous
//
#include <hip/hip_runtime.h>

// Problem constants (from reference)
#define HH 4096
#define WW 4096
#define NB 1024
#define NCHUNK 64
#define CROWS 64          // HH / NCHUNK
#define IOU_T 0.5f

typedef unsigned long long u64;

// ---------------- workspace layout ------------------------------------------
constexpr size_t OFF_COORDS = 0;                                   // int4 x NB (16 KB)
constexpr size_t OFF_RD     = OFF_COORDS + (size_t)NB * 16;        // int4 x HH (64 KB)
constexpr size_t OFF_PART   = OFF_RD     + (size_t)HH * 16;        // double x NCHUNK*WW (2 MB)
constexpr size_t OFF_SC64   = OFF_PART   + (size_t)NCHUNK * WW * 8;// double x NB
constexpr size_t OFF_ORDER  = OFF_SC64   + (size_t)NB * 8;         // int x NB
constexpr size_t OFF_BS     = OFF_ORDER  + (size_t)NB * 4;         // float4 x NB
constexpr size_t OFF_SSD    = OFF_BS     + (size_t)NB * 16;        // double x NB
constexpr size_t OFF_IOU    = OFF_SSD    + (size_t)NB * 8;         // u64 x NB*16 (128 KB)
constexpr size_t OFF_RECSC  = OFF_IOU    + (size_t)NB * 16 * 8;    // double x NB
constexpr size_t OFF_RECSEL = OFF_RECSC  + (size_t)NB * 8;         // u64 x NB*16 (128 KB)
constexpr size_t OFF_CC     = OFF_RECSEL + (size_t)NB * 16 * 8;    // float x 2048*WW (32 MB)
// total ~= 34.4 MB

// ---------------- kernels ---------------------------------------------------

// merged: box coords + row flags + exclusive scan + per-row x-range union.
// rowdesc[r] = { slot or -1, p0 (first col-pair), p1 (end col-pair), 0 }
__global__ void k_setup(const float* __restrict__ bbox, int4* coords,
                        int4* rowdesc) {
    __shared__ int lf[HH];        // 16 KB
    __shared__ int xlo[HH];       // 16 KB
    __shared__ int xhi[HH];       // 16 KB
    __shared__ int psum[256];
    int t = threadIdx.x;
    for (int k = t; k < HH; k += 256) { lf[k] = 0; xlo[k] = WW; xhi[k] = 0; }
    __syncthreads();
    for (int i = t; i < NB; i += 256) {
        float b0 = bbox[i * 4 + 0], b1 = bbox[i * 4 + 1];
        float b2 = bbox[i * 4 + 2], b3 = bbox[i * 4 + 3];
        int x1 = min(max((int)floorf(b0), 0), WW);
        int y1 = min(max((int)floorf(b1), 0), HH);
        int x2 = min(max((int)floorf(b2), 0), WW);
        int y2 = min(max((int)floorf(b3), 0), HH);
        coords[i] = make_int4(x1, y1, x2, y2);
        if (y1 >= 1) {
            lf[y1 - 1] = 1;                      // benign races: same value
            atomicMin(&xlo[y1 - 1], x1);
            atomicMax(&xhi[y1 - 1], x2);
        }
        if (y2 >= 1) {
            lf[y2 - 1] = 1;
            atomicMin(&xlo[y2 - 1], x1);
            atomicMax(&xhi[y2 - 1], x2);
        }
    }
    __syncthreads();
    int base = t * 16;
    int s = 0;
    for (int k = 0; k < 16; k++) s += lf[base + k];
    psum[t] = s;
    __syncthreads();
    if (t == 0) {
        int acc = 0;
        for (int k = 0; k < 256; k++) { int v = psum[k]; psum[k] = acc; acc += v; }
    }
    __syncthreads();
    int run = psum[t];
    for (int k = 0; k < 16; k++) {
        int r = base + k;
        int fl = lf[r];
        rowdesc[r] = make_int4(fl ? run : -1, xlo[r] >> 1, (xhi[r] + 1) >> 1, 0);
        run += fl;
    }
}

// fused staging: ONE read of probs. fp64 within-chunk column cumsum; emit fp32
// cumsum rows at flagged rows (only needed column segment); chunk totals ->
// part (fp64). float2 loads + 8-row unroll for latency coverage.
__global__ void __launch_bounds__(256) k_stage(const float* __restrict__ probs,
        const int4* __restrict__ rowdesc,
        double* __restrict__ part, float* __restrict__ Cc) {
    int tid = blockIdx.x * 256 + threadIdx.x;   // NCHUNK * WW/2 threads
    int c  = tid >> 11;          // chunk (WW/2 == 2048 col-pairs)
    int xg = tid & 2047;         // col-pair index
    const float2* p = (const float2*)probs + (size_t)c * CROWS * (WW / 2) + xg;
    const int4* rd = rowdesc + c * CROWS;
    float2* Cc2 = (float2*)Cc;
    double a0 = 0.0, a1 = 0.0;
    for (int r = 0; r < CROWS; r += 8) {
        float2 q[8];
        #pragma unroll
        for (int k = 0; k < 8; k++) q[k] = p[(size_t)(r + k) * (WW / 2)];
        #pragma unroll
        for (int k = 0; k < 8; k++) {
            a0 += (double)q[k].x; a1 += (double)q[k].y;
            int4 d = rd[r + k];
            if (d.x >= 0 && xg >= d.y && xg < d.z)
                Cc2[(size_t)d.x * (WW / 2) + xg] = make_float2((float)a0, (float)a1);
        }
    }
    ((double2*)part)[(size_t)c * (WW / 2) + xg] = make_double2(a0, a1);
}

// in-place exclusive scan of part along chunk axis (per column), grouped loads
__global__ void k_chunkscan(double* __restrict__ part) {
    int x = blockIdx.x * blockDim.x + threadIdx.x;   // WW threads
    double carry = 0.0;
    for (int g = 0; g < NCHUNK / 16; g++) {
        double v[16];
        #pragma unroll
        for (int k = 0; k < 16; k++) v[k] = part[(size_t)(g * 16 + k) * WW + x];
        #pragma unroll
        for (int k = 0; k < 16; k++) { double tv = v[k]; v[k] = carry; carry += tv; }
        #pragma unroll
        for (int k = 0; k < 16; k++) part[(size_t)(g * 16 + k) * WW + x] = v[k];
    }
}

// per-box rectangle sum: one wave per box; column value = within-chunk fp32
// cumsum row + fp64 chunk prefix. fp64 shuffle-reduce.
__global__ void __launch_bounds__(64) k_boxsum(const int4* __restrict__ coords,
                         const float* __restrict__ obj,
                         const int4* __restrict__ rowdesc, const float* __restrict__ Cc,
                         const double* __restrict__ part,
                         double* sc64) {
    int i = blockIdx.x;
    int lane = threadIdx.x;
    int4 cd = coords[i]; // x=x1, y=y1, z=x2, w=y2
    bool h1 = (cd.y >= 1), h2 = (cd.w >= 1);
    int s1 = h1 ? rowdesc[cd.y - 1].x : 0;
    int s2 = h2 ? rowdesc[cd.w - 1].x : 0;
    const float*  r2 = Cc   + (size_t)(h2 ? s2 : 0) * WW;
    const double* q2 = part + (size_t)(h2 ? ((cd.w - 1) >> 6) : 0) * WW;
    const float*  r1 = Cc   + (size_t)(h1 ? s1 : 0) * WW;
    const double* q1 = part + (size_t)(h1 ? ((cd.y - 1) >> 6) : 0) * WW;
    double s = 0.0;
    for (int x = cd.x + lane; x < cd.z; x += 64) {
        double v2 = h2 ? ((double)r2[x] + q2[x]) : 0.0;
        double v1 = h1 ? ((double)r1[x] + q1[x]) : 0.0;
        s += (v2 - v1);
    }
    #pragma unroll
    for (int off = 32; off > 0; off >>= 1) s += __shfl_down(s, off);
    if (lane == 0) {
        long long cnt = (long long)(cd.w - cd.y) * (long long)(cd.z - cd.x);
        if (cnt < 1) cnt = 1;
        double box = s / (double)cnt;
        sc64[i] = 0.5 * ((double)obj[i] + box);
    }
}

// stable descending rank sort, 8 blocks x 128 threads (R5: single 1024-thread
// block was 43 us — 1 CU, LDS-latency-bound). Per-block LDS score copy;
// 8x-unrolled j loop gives 8 independent LDS reads in flight.
__global__ void __launch_bounds__(128) k_rank(const double* __restrict__ sc64,
                                              int* __restrict__ order) {
    __shared__ double s[NB];   // 8 KB
    int t = threadIdx.x;
    for (int k = t; k < NB; k += 128) s[k] = sc64[k];
    __syncthreads();
    int i = blockIdx.x * 128 + t;
    double si = s[i];
    int rank = 0;
    #pragma unroll 8
    for (int j = 0; j < NB; j++) {
        double sj = s[j];
        rank += (sj > si) || (sj == si && j < i);
    }
    order[rank] = i;
}

__global__ void __launch_bounds__(256) k_gather(const int* __restrict__ order,
                        const float* __restrict__ bbox,
                        const double* __restrict__ sc64,
                        float4* bs, double* ssd) {
    int i = blockIdx.x * 256 + threadIdx.x;
    int o = order[i];
    bs[i] = ((const float4*)bbox)[o];
    ssd[i] = sc64[o];
}

// IoU(bs_i, bs_j) > 0.5 bit matrix, one u64 word per 64 j's via ballot
__global__ void k_iou(const float4* __restrict__ bs, u64* __restrict__ ioub) {
    int tid = blockIdx.x * blockDim.x + threadIdx.x; // NB*NB threads
    int i = tid >> 10;
    int j = tid & (NB - 1);
    float4 a = bs[i], b = bs[j];
    float ai = (a.z - a.x) * (a.w - a.y);
    float aj = (b.z - b.x) * (b.w - b.y);
    float ix1 = fmaxf(a.x, b.x), iy1 = fmaxf(a.y, b.y);
    float ix2 = fminf(a.z, b.z), iy2 = fminf(a.w, b.w);
    float iw = fmaxf(ix2 - ix1, 0.0f), ih = fmaxf(iy2 - iy1, 0.0f);
    float inter = iw * ih;
    float iou_v = inter / (ai + aj - inter);
    bool bit = iou_v > IOU_T;
    u64 m = __ballot(bit);
    if ((threadIdx.x & 63) == 0) ioub[(size_t)i * 16 + (j >> 6)] = m;
}

// greedy grouping, one thread per start, 16 blocks x 64 threads.
// Register masks + ctz scan walk the SAME increasing-j greedy order as the
// reference (inc updated per add). Record rule: rec iff size==K and the
// last add happened at j <= NB-2 (check-before-add semantics).
__global__ void __launch_bounds__(64) k_group(const u64* __restrict__ ioub,
                        const double* __restrict__ ssd,
                        const int* __restrict__ counts,
                        double* __restrict__ recsc,
                        u64* __restrict__ recsel) {
    __shared__ double ssd_s[NB];   // 8 KB
    int t = threadIdx.x;
    int i = blockIdx.x * 64 + t;   // start index
    for (int k = t; k < NB; k += 64) ssd_s[k] = ssd[k];
    __syncthreads();
    int K = counts[0];
    u64 inc[16], sel[16];
    int wi = i >> 6, bi = i & 63;
    #pragma unroll
    for (int w = 0; w < 16; w++) {
        inc[w] = ioub[(size_t)i * 16 + w];
        sel[w] = (w == wi) ? (1ULL << bi) : 0ULL;
    }
    int size = 1;
    double score = ssd_s[i];
    int last = i;
    #pragma unroll
    for (int w = 0; w < 16; w++) {
        if (w < wi || size >= K) continue;
        u64 avail = ~inc[w];
        if (w == wi) avail &= (bi == 63) ? 0ULL : (~0ULL << (bi + 1));
        while (avail != 0ULL && size < K) {
            int b = __builtin_ctzll(avail);
            int j = (w << 6) + b;
            sel[w] |= 1ULL << b;
            size++;
            score += ssd_s[j];
            last = j;
            const u64* rj = ioub + (size_t)j * 16;
            #pragma unroll
            for (int w2 = 0; w2 < 16; w2++) inc[w2] |= rj[w2];
            avail &= ~inc[w];          // row j's own bits clear b et al.
            avail &= ~(1ULL << b);     // safety
        }
    }
    int rec = (size == K) && (last < NB - 1);
    recsc[i] = rec ? score : -1e300;
    #pragma unroll
    for (int w = 0; w < 16; w++) recsel[(size_t)i * 16 + w] = sel[w];
}

// best = max recorded score, ties -> LAST index (reference's last-argmax rule)
__global__ void __launch_bounds__(1024) k_final(const double* __restrict__ recsc,
                        const u64* __restrict__ recsel,
                        const double* __restrict__ ssd, float* __restrict__ out) {
    __shared__ double bsc[NB];
    __shared__ int bidx[NB];
    __shared__ int best_s, any_s;
    int t = threadIdx.x; // 1024 threads
    bsc[t] = recsc[t];
    bidx[t] = t;
    __syncthreads();
    for (int st = 512; st > 0; st >>= 1) {
        if (t < st) {
            double a = bsc[t], b2 = bsc[t + st];
            if (b2 > a || (b2 == a && bidx[t + st] > bidx[t])) {
                bsc[t] = b2;
                bidx[t] = bidx[t + st];
            }
        }
        __syncthreads();
    }
    if (t == 0) { best_s = bidx[0]; any_s = (bsc[0] > -1e299) ? 1 : 0; }
    __syncthreads();
    float v = 0.0f;
    if (any_s && ((recsel[(size_t)best_s * 16 + (t >> 6)] >> (t & 63)) & 1ULL))
        v = (float)ssd[t];
    out[t] = v;
}

// ---------------- host entry ------------------------------------------------

extern "C" void kernel_launch(void* const* d_in, const int* in_sizes, int n_in,
                              void* d_out, int out_size, void* d_ws, size_t ws_size,
                              hipStream_t stream) {
    const float* bbox  = (const float*)d_in[0];
    const float* obj   = (const float*)d_in[1];
    const float* probs = (const float*)d_in[2];
    const int*   counts = (const int*)d_in[3];
    float* out = (float*)d_out;

    char* w = (char*)d_ws;
    int4*   coords  = (int4*)(w + OFF_COORDS);
    int4*   rowdesc = (int4*)(w + OFF_RD);
    double* part    = (double*)(w + OFF_PART);
    double* sc64    = (double*)(w + OFF_SC64);
    int*    order   = (int*)(w + OFF_ORDER);
    float4* bs      = (float4*)(w + OFF_BS);
    double* ssd     = (double*)(w + OFF_SSD);
    u64*    ioub    = (u64*)(w + OFF_IOU);
    double* recsc   = (double*)(w + OFF_RECSC);
    u64*    recsel  = (u64*)(w + OFF_RECSEL);
    float*  Cc      = (float*)(w + OFF_CC);

    k_setup<<<1, 256, 0, stream>>>(bbox, coords, rowdesc);
    k_stage<<<(NCHUNK * WW / 2) / 256, 256, 0, stream>>>(probs, rowdesc, part, Cc);
    k_chunkscan<<<WW / 256, 256, 0, stream>>>(part);
    k_boxsum<<<NB, 64, 0, stream>>>(coords, obj, rowdesc, Cc, part, sc64);
    k_rank<<<NB / 128, 128, 0, stream>>>(sc64, order);
    k_gather<<<NB / 256, 256, 0, stream>>>(order, bbox, sc64, bs, ssd);
    k_iou<<<(NB * NB) / 256, 256, 0, stream>>>(bs, ioub);
    k_group<<<NB / 64, 64, 0, stream>>>(ioub, ssd, counts, recsc, recsel);
    k_final<<<1, 1024, 0, stream>>>(recsc, recsel, ssd, out);
}

// Round 7
// 182.305 us; speedup vs baseline: 1.2465x; 1.0346x over previous
//
#include <hip/hip_runtime.h>

// Problem constants (from reference)
#define HH 4096
#define WW 4096
#define NB 1024
#define NCHUNK 64
#define CROWS 64          // HH / NCHUNK
#define IOU_T 0.5f

typedef unsigned long long u64;

// ---------------- workspace layout ------------------------------------------
constexpr size_t OFF_COORDS = 0;                                   // int4 x NB (16 KB)
constexpr size_t OFF_RD     = OFF_COORDS + (size_t)NB * 16;        // int4 x HH (64 KB)
constexpr size_t OFF_PART   = OFF_RD     + (size_t)HH * 16;        // double x NCHUNK*WW (2 MB)
constexpr size_t OFF_SC64   = OFF_PART   + (size_t)NCHUNK * WW * 8;// double x NB
constexpr size_t OFF_ORDER  = OFF_SC64   + (size_t)NB * 8;         // int x NB
constexpr size_t OFF_IOU    = OFF_ORDER  + (size_t)NB * 4;         // u64 x NB*16 (128 KB)
constexpr size_t OFF_RECSC  = OFF_IOU    + (size_t)NB * 16 * 8;    // double x NB
constexpr size_t OFF_RECSEL = OFF_RECSC  + (size_t)NB * 8;         // u64 x NB*16 (128 KB)
constexpr size_t OFF_CC     = OFF_RECSEL + (size_t)NB * 16 * 8;    // float x 2048*WW (32 MB)
// total ~= 34.4 MB

// ---------------- kernels ---------------------------------------------------

// merged: box coords + row flags + exclusive scan + per-row x-range union.
// rowdesc[r] = { slot or -1, q0 (first col-quad), q1 (end col-quad), 0 }
__global__ void __launch_bounds__(1024) k_setup(const float* __restrict__ bbox,
                        int4* coords, int4* rowdesc) {
    __shared__ int lf[HH];        // 16 KB
    __shared__ int xlo[HH];       // 16 KB
    __shared__ int xhi[HH];       // 16 KB
    __shared__ int psum[256];
    int t = threadIdx.x;          // 1024 threads
    for (int k = t; k < HH; k += 1024) { lf[k] = 0; xlo[k] = WW; xhi[k] = 0; }
    __syncthreads();
    {
        int i = t;
        if (i < NB) {
            float b0 = bbox[i * 4 + 0], b1 = bbox[i * 4 + 1];
            float b2 = bbox[i * 4 + 2], b3 = bbox[i * 4 + 3];
            int x1 = min(max((int)floorf(b0), 0), WW);
            int y1 = min(max((int)floorf(b1), 0), HH);
            int x2 = min(max((int)floorf(b2), 0), WW);
            int y2 = min(max((int)floorf(b3), 0), HH);
            coords[i] = make_int4(x1, y1, x2, y2);
            if (y1 >= 1) {
                lf[y1 - 1] = 1;                      // benign races: same value
                atomicMin(&xlo[y1 - 1], x1);
                atomicMax(&xhi[y1 - 1], x2);
            }
            if (y2 >= 1) {
                lf[y2 - 1] = 1;
                atomicMin(&xlo[y2 - 1], x1);
                atomicMax(&xhi[y2 - 1], x2);
            }
        }
    }
    __syncthreads();
    if (t < 256) {
        int base = t * 16;
        int s = 0;
        for (int k = 0; k < 16; k++) s += lf[base + k];
        psum[t] = s;
    }
    __syncthreads();
    if (t == 0) {
        int acc = 0;
        for (int k = 0; k < 256; k++) { int v = psum[k]; psum[k] = acc; acc += v; }
    }
    __syncthreads();
    if (t < 256) {
        int base = t * 16;
        int run = psum[t];
        for (int k = 0; k < 16; k++) {
            int r = base + k;
            int fl = lf[r];
            rowdesc[r] = make_int4(fl ? run : -1, xlo[r] >> 2, (xhi[r] + 3) >> 2, 0);
            run += fl;
        }
    }
}

// fused staging: ONE read of probs, float4 (16 B/lane) loads. fp64
// within-chunk column cumsum; emit fp32 cumsum rows at flagged rows (only
// needed column segment); chunk totals -> part (fp64).
__global__ void __launch_bounds__(256) k_stage(const float* __restrict__ probs,
        const int4* __restrict__ rowdesc,
        double* __restrict__ part, float* __restrict__ Cc) {
    int tid = blockIdx.x * 256 + threadIdx.x;   // NCHUNK * WW/4 threads
    int c  = tid >> 10;          // chunk (WW/4 == 1024 col-quads)
    int xq = tid & 1023;         // col-quad index
    const float4* p = (const float4*)probs + (size_t)c * CROWS * (WW / 4) + xq;
    const int4* rd = rowdesc + c * CROWS;
    float4* Cc4 = (float4*)Cc;
    double a0 = 0.0, a1 = 0.0, a2 = 0.0, a3 = 0.0;
    for (int r = 0; r < CROWS; r += 8) {
        float4 q[8];
        #pragma unroll
        for (int k = 0; k < 8; k++) q[k] = p[(size_t)(r + k) * (WW / 4)];
        #pragma unroll
        for (int k = 0; k < 8; k++) {
            a0 += (double)q[k].x; a1 += (double)q[k].y;
            a2 += (double)q[k].z; a3 += (double)q[k].w;
            int4 d = rd[r + k];
            if (d.x >= 0 && xq >= d.y && xq < d.z)
                Cc4[(size_t)d.x * (WW / 4) + xq] =
                    make_float4((float)a0, (float)a1, (float)a2, (float)a3);
        }
    }
    double2* pp = (double2*)(part + (size_t)c * WW) + xq * 2;
    pp[0] = make_double2(a0, a1);
    pp[1] = make_double2(a2, a3);
}

// in-place exclusive scan of part along chunk axis (per column), grouped loads
__global__ void k_chunkscan(double* __restrict__ part) {
    int x = blockIdx.x * blockDim.x + threadIdx.x;   // WW threads
    double carry = 0.0;
    for (int g = 0; g < NCHUNK / 16; g++) {
        double v[16];
        #pragma unroll
        for (int k = 0; k < 16; k++) v[k] = part[(size_t)(g * 16 + k) * WW + x];
        #pragma unroll
        for (int k = 0; k < 16; k++) { double tv = v[k]; v[k] = carry; carry += tv; }
        #pragma unroll
        for (int k = 0; k < 16; k++) part[(size_t)(g * 16 + k) * WW + x] = v[k];
    }
}

// per-box rectangle sum: one wave per box; column value = within-chunk fp32
// cumsum row + fp64 chunk prefix. fp64 shuffle-reduce.
__global__ void __launch_bounds__(64) k_boxsum(const int4* __restrict__ coords,
                         const float* __restrict__ obj,
                         const int4* __restrict__ rowdesc, const float* __restrict__ Cc,
                         const double* __restrict__ part,
                         double* sc64) {
    int i = blockIdx.x;
    int lane = threadIdx.x;
    int4 cd = coords[i]; // x=x1, y=y1, z=x2, w=y2
    bool h1 = (cd.y >= 1), h2 = (cd.w >= 1);
    int s1 = h1 ? rowdesc[cd.y - 1].x : 0;
    int s2 = h2 ? rowdesc[cd.w - 1].x : 0;
    const float*  r2 = Cc   + (size_t)(h2 ? s2 : 0) * WW;
    const double* q2 = part + (size_t)(h2 ? ((cd.w - 1) >> 6) : 0) * WW;
    const float*  r1 = Cc   + (size_t)(h1 ? s1 : 0) * WW;
    const double* q1 = part + (size_t)(h1 ? ((cd.y - 1) >> 6) : 0) * WW;
    double s = 0.0;
    for (int x = cd.x + lane; x < cd.z; x += 64) {
        double v2 = h2 ? ((double)r2[x] + q2[x]) : 0.0;
        double v1 = h1 ? ((double)r1[x] + q1[x]) : 0.0;
        s += (v2 - v1);
    }
    #pragma unroll
    for (int off = 32; off > 0; off >>= 1) s += __shfl_down(s, off);
    if (lane == 0) {
        long long cnt = (long long)(cd.w - cd.y) * (long long)(cd.z - cd.x);
        if (cnt < 1) cnt = 1;
        double box = s / (double)cnt;
        sc64[i] = 0.5 * ((double)obj[i] + box);
    }
}

// stable descending rank sort, 8 blocks x 128 threads; per-block LDS score
// copy; unrolled j loop keeps 8 independent LDS reads in flight.
__global__ void __launch_bounds__(128) k_rank(const double* __restrict__ sc64,
                                              int* __restrict__ order) {
    __shared__ double s[NB];   // 8 KB
    int t = threadIdx.x;
    for (int k = t; k < NB; k += 128) s[k] = sc64[k];
    __syncthreads();
    int i = blockIdx.x * 128 + t;
    double si = s[i];
    int rank = 0;
    #pragma unroll 8
    for (int j = 0; j < NB; j++) {
        double sj = s[j];
        rank += (sj > si) || (sj == si && j < i);
    }
    order[rank] = i;
}

// IoU(sorted_i, sorted_j) > 0.5 bit matrix via order-indirection (order 4 KB,
// bbox 16 KB — L1/L2 resident). One u64 word per 64 j's via ballot.
__global__ void k_iou(const int* __restrict__ order, const float* __restrict__ bbox,
                      u64* __restrict__ ioub) {
    int tid = blockIdx.x * blockDim.x + threadIdx.x; // NB*NB threads
    int i = tid >> 10;
    int j = tid & (NB - 1);
    float4 a = ((const float4*)bbox)[order[i]];
    float4 b = ((const float4*)bbox)[order[j]];
    float ai = (a.z - a.x) * (a.w - a.y);
    float aj = (b.z - b.x) * (b.w - b.y);
    float ix1 = fmaxf(a.x, b.x), iy1 = fmaxf(a.y, b.y);
    float ix2 = fminf(a.z, b.z), iy2 = fminf(a.w, b.w);
    float iw = fmaxf(ix2 - ix1, 0.0f), ih = fmaxf(iy2 - iy1, 0.0f);
    float inter = iw * ih;
    float iou_v = inter / (ai + aj - inter);
    bool bit = iou_v > IOU_T;
    u64 m = __ballot(bit);
    if ((threadIdx.x & 63) == 0) ioub[(size_t)i * 16 + (j >> 6)] = m;
}

// greedy grouping, one thread per start, 16 blocks x 64 threads.
// Register masks + ctz scan walk the SAME increasing-j greedy order as the
// reference (inc updated per add). Record rule: rec iff size==K and the
// last add happened at j <= NB-2 (check-before-add semantics).
__global__ void __launch_bounds__(64) k_group(const u64* __restrict__ ioub,
                        const int* __restrict__ order,
                        const double* __restrict__ sc64,
                        const int* __restrict__ counts,
                        double* __restrict__ recsc,
                        u64* __restrict__ recsel) {
    __shared__ double ssd_s[NB];   // 8 KB, sorted scores
    int t = threadIdx.x;
    int i = blockIdx.x * 64 + t;   // start index (sorted domain)
    for (int k = t; k < NB; k += 64) ssd_s[k] = sc64[order[k]];
    __syncthreads();
    int K = counts[0];
    u64 inc[16], sel[16];
    int wi = i >> 6, bi = i & 63;
    #pragma unroll
    for (int w = 0; w < 16; w++) {
        inc[w] = ioub[(size_t)i * 16 + w];
        sel[w] = (w == wi) ? (1ULL << bi) : 0ULL;
    }
    int size = 1;
    double score = ssd_s[i];
    int last = i;
    #pragma unroll
    for (int w = 0; w < 16; w++) {
        if (w < wi || size >= K) continue;
        u64 avail = ~inc[w];
        if (w == wi) avail &= (bi == 63) ? 0ULL : (~0ULL << (bi + 1));
        while (avail != 0ULL && size < K) {
            int b = __builtin_ctzll(avail);
            int j = (w << 6) + b;
            sel[w] |= 1ULL << b;
            size++;
            score += ssd_s[j];
            last = j;
            const u64* rj = ioub + (size_t)j * 16;
            #pragma unroll
            for (int w2 = 0; w2 < 16; w2++) inc[w2] |= rj[w2];
            avail &= ~inc[w];          // row j's own bits clear b et al.
            avail &= ~(1ULL << b);     // safety
        }
    }
    int rec = (size == K) && (last < NB - 1);
    recsc[i] = rec ? score : -1e300;
    #pragma unroll
    for (int w = 0; w < 16; w++) recsel[(size_t)i * 16 + w] = sel[w];
}

// best = max recorded score, ties -> LAST index (reference's last-argmax rule)
__global__ void __launch_bounds__(1024) k_final(const double* __restrict__ recsc,
                        const u64* __restrict__ recsel,
                        const int* __restrict__ order,
                        const double* __restrict__ sc64, float* __restrict__ out) {
    __shared__ double bsc[NB];
    __shared__ int bidx[NB];
    __shared__ int best_s, any_s;
    int t = threadIdx.x; // 1024 threads
    bsc[t] = recsc[t];
    bidx[t] = t;
    __syncthreads();
    for (int st = 512; st > 0; st >>= 1) {
        if (t < st) {
            double a = bsc[t], b2 = bsc[t + st];
            if (b2 > a || (b2 == a && bidx[t + st] > bidx[t])) {
                bsc[t] = b2;
                bidx[t] = bidx[t + st];
            }
        }
        __syncthreads();
    }
    if (t == 0) { best_s = bidx[0]; any_s = (bsc[0] > -1e299) ? 1 : 0; }
    __syncthreads();
    float v = 0.0f;
    if (any_s && ((recsel[(size_t)best_s * 16 + (t >> 6)] >> (t & 63)) & 1ULL))
        v = (float)sc64[order[t]];
    out[t] = v;
}

// ---------------- host entry ------------------------------------------------

extern "C" void kernel_launch(void* const* d_in, const int* in_sizes, int n_in,
                              void* d_out, int out_size, void* d_ws, size_t ws_size,
                              hipStream_t stream) {
    const float* bbox  = (const float*)d_in[0];
    const float* obj   = (const float*)d_in[1];
    const float* probs = (const float*)d_in[2];
    const int*   counts = (const int*)d_in[3];
    float* out = (float*)d_out;

    char* w = (char*)d_ws;
    int4*   coords  = (int4*)(w + OFF_COORDS);
    int4*   rowdesc = (int4*)(w + OFF_RD);
    double* part    = (double*)(w + OFF_PART);
    double* sc64    = (double*)(w + OFF_SC64);
    int*    order   = (int*)(w + OFF_ORDER);
    u64*    ioub    = (u64*)(w + OFF_IOU);
    double* recsc   = (double*)(w + OFF_RECSC);
    u64*    recsel  = (u64*)(w + OFF_RECSEL);
    float*  Cc      = (float*)(w + OFF_CC);

    k_setup<<<1, 1024, 0, stream>>>(bbox, coords, rowdesc);
    k_stage<<<(NCHUNK * WW / 4) / 256, 256, 0, stream>>>(probs, rowdesc, part, Cc);
    k_chunkscan<<<WW / 256, 256, 0, stream>>>(part);
    k_boxsum<<<NB, 64, 0, stream>>>(coords, obj, rowdesc, Cc, part, sc64);
    k_rank<<<NB / 128, 128, 0, stream>>>(sc64, order);
    k_iou<<<(NB * NB) / 256, 256, 0, stream>>>(order, bbox, ioub);
    k_group<<<NB / 64, 64, 0, stream>>>(ioub, order, sc64, counts, recsc, recsel);
    k_final<<<1, 1024, 0, stream>>>(recsc, recsel, order, sc64, out);
}

// Round 8
// 179.687 us; speedup vs baseline: 1.2646x; 1.0146x over previous
//
#include <hip/hip_runtime.h>

// Problem constants (from reference)
#define HH 4096
#define WW 4096
#define NB 1024
#define NCHUNK 64
#define CROWS 64          // HH / NCHUNK
#define IOU_T 0.5f

typedef unsigned long long u64;

// ---------------- workspace layout ------------------------------------------
constexpr size_t OFF_COORDS = 0;                                   // int4 x NB (16 KB)
constexpr size_t OFF_RD     = OFF_COORDS + (size_t)NB * 16;        // int4 x HH (64 KB)
constexpr size_t OFF_PART   = OFF_RD     + (size_t)HH * 16;        // double x NCHUNK*WW (2 MB)
constexpr size_t OFF_SC64   = OFF_PART   + (size_t)NCHUNK * WW * 8;// double x NB
constexpr size_t OFF_ORDER  = OFF_SC64   + (size_t)NB * 8;         // int x NB
constexpr size_t OFF_CTR    = OFF_ORDER  + (size_t)NB * 4;         // int x 16 (64 B)
constexpr size_t OFF_IOU    = OFF_CTR    + 64;                     // u64 x NB*16 (128 KB)
constexpr size_t OFF_RECSC  = OFF_IOU    + (size_t)NB * 16 * 8;    // double x NB
constexpr size_t OFF_RECSEL = OFF_RECSC  + (size_t)NB * 8;         // u64 x NB*16 (128 KB)
constexpr size_t OFF_CC     = OFF_RECSEL + (size_t)NB * 16 * 8;    // float x 2048*WW (32 MB)
// total ~= 34.4 MB

// ---------------- kernels ---------------------------------------------------

// merged: box coords + row flags + exclusive scan + per-row x-range union.
// Also zeroes the k_group completion counter (graph-safe per-call reset).
// rowdesc[r] = { slot or -1, q0 (first col-quad), q1 (end col-quad), 0 }
__global__ void __launch_bounds__(1024) k_setup(const float* __restrict__ bbox,
                        int4* coords, int4* rowdesc, int* ctr) {
    __shared__ int lf[HH];        // 16 KB
    __shared__ int xlo[HH];       // 16 KB
    __shared__ int xhi[HH];       // 16 KB
    __shared__ int psum[256];
    int t = threadIdx.x;          // 1024 threads
    if (t == 0) *ctr = 0;
    for (int k = t; k < HH; k += 1024) { lf[k] = 0; xlo[k] = WW; xhi[k] = 0; }
    __syncthreads();
    if (t < NB) {
        int i = t;
        float b0 = bbox[i * 4 + 0], b1 = bbox[i * 4 + 1];
        float b2 = bbox[i * 4 + 2], b3 = bbox[i * 4 + 3];
        int x1 = min(max((int)floorf(b0), 0), WW);
        int y1 = min(max((int)floorf(b1), 0), HH);
        int x2 = min(max((int)floorf(b2), 0), WW);
        int y2 = min(max((int)floorf(b3), 0), HH);
        coords[i] = make_int4(x1, y1, x2, y2);
        if (y1 >= 1) {
            lf[y1 - 1] = 1;                      // benign races: same value
            atomicMin(&xlo[y1 - 1], x1);
            atomicMax(&xhi[y1 - 1], x2);
        }
        if (y2 >= 1) {
            lf[y2 - 1] = 1;
            atomicMin(&xlo[y2 - 1], x1);
            atomicMax(&xhi[y2 - 1], x2);
        }
    }
    __syncthreads();
    if (t < 256) {
        int base = t * 16;
        int s = 0;
        for (int k = 0; k < 16; k++) s += lf[base + k];
        psum[t] = s;
    }
    __syncthreads();
    // exclusive scan of psum[256] by wave 0 (R7: serial t==0 loop)
    if (t < 64) {
        int v0 = psum[t * 4], v1 = psum[t * 4 + 1];
        int v2 = psum[t * 4 + 2], v3 = psum[t * 4 + 3];
        int lsum = v0 + v1 + v2 + v3;
        int incs = lsum;
        #pragma unroll
        for (int off = 1; off < 64; off <<= 1) {
            int n = __shfl_up(incs, off);
            if (t >= off) incs += n;
        }
        int ex = incs - lsum;
        psum[t * 4]     = ex;
        psum[t * 4 + 1] = ex + v0;
        psum[t * 4 + 2] = ex + v0 + v1;
        psum[t * 4 + 3] = ex + v0 + v1 + v2;
    }
    __syncthreads();
    if (t < 256) {
        int base = t * 16;
        int run = psum[t];
        for (int k = 0; k < 16; k++) {
            int r = base + k;
            int fl = lf[r];
            rowdesc[r] = make_int4(fl ? run : -1, xlo[r] >> 2, (xhi[r] + 3) >> 2, 0);
            run += fl;
        }
    }
}

// fused staging: ONE read of probs, float4 (16 B/lane) loads. fp64
// within-chunk column cumsum; emit fp32 cumsum rows at flagged rows (only
// needed column segment); chunk totals -> part (fp64). rowdesc rows for the
// block's chunk staged in LDS (uniform across the block -> broadcast reads).
__global__ void __launch_bounds__(256) k_stage(const float* __restrict__ probs,
        const int4* __restrict__ rowdesc,
        double* __restrict__ part, float* __restrict__ Cc) {
    __shared__ int4 rd_s[CROWS];
    int tid = blockIdx.x * 256 + threadIdx.x;   // NCHUNK * WW/4 threads
    int c  = tid >> 10;          // chunk (WW/4 == 1024 col-quads); uniform per block
    int xq = tid & 1023;         // col-quad index
    if (threadIdx.x < CROWS) rd_s[threadIdx.x] = rowdesc[c * CROWS + threadIdx.x];
    __syncthreads();
    const float4* p = (const float4*)probs + (size_t)c * CROWS * (WW / 4) + xq;
    float4* Cc4 = (float4*)Cc;
    double a0 = 0.0, a1 = 0.0, a2 = 0.0, a3 = 0.0;
    for (int r = 0; r < CROWS; r += 8) {
        float4 q[8];
        #pragma unroll
        for (int k = 0; k < 8; k++) q[k] = p[(size_t)(r + k) * (WW / 4)];
        #pragma unroll
        for (int k = 0; k < 8; k++) {
            a0 += (double)q[k].x; a1 += (double)q[k].y;
            a2 += (double)q[k].z; a3 += (double)q[k].w;
            int4 d = rd_s[r + k];
            if (d.x >= 0 && xq >= d.y && xq < d.z)
                Cc4[(size_t)d.x * (WW / 4) + xq] =
                    make_float4((float)a0, (float)a1, (float)a2, (float)a3);
        }
    }
    double2* pp = (double2*)(part + (size_t)c * WW) + xq * 2;
    pp[0] = make_double2(a0, a1);
    pp[1] = make_double2(a2, a3);
}

// in-place exclusive scan of part along chunk axis (per column), grouped loads
__global__ void k_chunkscan(double* __restrict__ part) {
    int x = blockIdx.x * blockDim.x + threadIdx.x;   // WW threads
    double carry = 0.0;
    for (int g = 0; g < NCHUNK / 16; g++) {
        double v[16];
        #pragma unroll
        for (int k = 0; k < 16; k++) v[k] = part[(size_t)(g * 16 + k) * WW + x];
        #pragma unroll
        for (int k = 0; k < 16; k++) { double tv = v[k]; v[k] = carry; carry += tv; }
        #pragma unroll
        for (int k = 0; k < 16; k++) part[(size_t)(g * 16 + k) * WW + x] = v[k];
    }
}

// per-box rectangle sum: one wave per box; column value = within-chunk fp32
// cumsum row + fp64 chunk prefix. fp64 shuffle-reduce.
__global__ void __launch_bounds__(64) k_boxsum(const int4* __restrict__ coords,
                         const float* __restrict__ obj,
                         const int4* __restrict__ rowdesc, const float* __restrict__ Cc,
                         const double* __restrict__ part,
                         double* sc64) {
    int i = blockIdx.x;
    int lane = threadIdx.x;
    int4 cd = coords[i]; // x=x1, y=y1, z=x2, w=y2
    bool h1 = (cd.y >= 1), h2 = (cd.w >= 1);
    int s1 = h1 ? rowdesc[cd.y - 1].x : 0;
    int s2 = h2 ? rowdesc[cd.w - 1].x : 0;
    const float*  r2 = Cc   + (size_t)(h2 ? s2 : 0) * WW;
    const double* q2 = part + (size_t)(h2 ? ((cd.w - 1) >> 6) : 0) * WW;
    const float*  r1 = Cc   + (size_t)(h1 ? s1 : 0) * WW;
    const double* q1 = part + (size_t)(h1 ? ((cd.y - 1) >> 6) : 0) * WW;
    double s = 0.0;
    for (int x = cd.x + lane; x < cd.z; x += 64) {
        double v2 = h2 ? ((double)r2[x] + q2[x]) : 0.0;
        double v1 = h1 ? ((double)r1[x] + q1[x]) : 0.0;
        s += (v2 - v1);
    }
    #pragma unroll
    for (int off = 32; off > 0; off >>= 1) s += __shfl_down(s, off);
    if (lane == 0) {
        long long cnt = (long long)(cd.w - cd.y) * (long long)(cd.z - cd.x);
        if (cnt < 1) cnt = 1;
        double box = s / (double)cnt;
        sc64[i] = 0.5 * ((double)obj[i] + box);
    }
}

// stable descending rank sort, 8 blocks x 128 threads; per-block LDS score
// copy; unrolled j loop keeps 8 independent LDS reads in flight.
__global__ void __launch_bounds__(128) k_rank(const double* __restrict__ sc64,
                                              int* __restrict__ order) {
    __shared__ double s[NB];   // 8 KB
    int t = threadIdx.x;
    for (int k = t; k < NB; k += 128) s[k] = sc64[k];
    __syncthreads();
    int i = blockIdx.x * 128 + t;
    double si = s[i];
    int rank = 0;
    #pragma unroll 8
    for (int j = 0; j < NB; j++) {
        double sj = s[j];
        rank += (sj > si) || (sj == si && j < i);
    }
    order[rank] = i;
}

// IoU(sorted_i, sorted_j) > 0.5 bit matrix via order-indirection (order 4 KB,
// bbox 16 KB — L1/L2 resident). One u64 word per 64 j's via ballot.
__global__ void k_iou(const int* __restrict__ order, const float* __restrict__ bbox,
                      u64* __restrict__ ioub) {
    int tid = blockIdx.x * blockDim.x + threadIdx.x; // NB*NB threads
    int i = tid >> 10;
    int j = tid & (NB - 1);
    float4 a = ((const float4*)bbox)[order[i]];
    float4 b = ((const float4*)bbox)[order[j]];
    float ai = (a.z - a.x) * (a.w - a.y);
    float aj = (b.z - b.x) * (b.w - b.y);
    float ix1 = fmaxf(a.x, b.x), iy1 = fmaxf(a.y, b.y);
    float ix2 = fminf(a.z, b.z), iy2 = fminf(a.w, b.w);
    float iw = fmaxf(ix2 - ix1, 0.0f), ih = fmaxf(iy2 - iy1, 0.0f);
    float inter = iw * ih;
    float iou_v = inter / (ai + aj - inter);
    bool bit = iou_v > IOU_T;
    u64 m = __ballot(bit);
    if ((threadIdx.x & 63) == 0) ioub[(size_t)i * 16 + (j >> 6)] = m;
}

// greedy grouping, one thread per start, 16 blocks x 64 threads, with the
// final last-argmax + output scatter fused into the LAST block to finish
// (device-scope atomic counter; R4 showed single-block grouping is the thing
// to avoid — grouping itself stays on 16 CUs).
// Register masks + ctz scan walk the SAME increasing-j greedy order as the
// reference (inc updated per add). Record rule: rec iff size==K and the
// last add happened at j <= NB-2 (check-before-add semantics).
__global__ void __launch_bounds__(64) k_group(const u64* __restrict__ ioub,
                        const int* __restrict__ order,
                        const double* __restrict__ sc64,
                        const int* __restrict__ counts,
                        double* __restrict__ recsc,
                        u64* __restrict__ recsel,
                        int* __restrict__ ctr,
                        float* __restrict__ out) {
    __shared__ double ssd_s[NB];   // 8 KB, sorted scores
    __shared__ int lastflag;
    int t = threadIdx.x;
    int i = blockIdx.x * 64 + t;   // start index (sorted domain)
    for (int k = t; k < NB; k += 64) ssd_s[k] = sc64[order[k]];
    __syncthreads();
    int K = counts[0];
    u64 inc[16], sel[16];
    int wi = i >> 6, bi = i & 63;
    #pragma unroll
    for (int w = 0; w < 16; w++) {
        inc[w] = ioub[(size_t)i * 16 + w];
        sel[w] = (w == wi) ? (1ULL << bi) : 0ULL;
    }
    int size = 1;
    double score = ssd_s[i];
    int last = i;
    #pragma unroll
    for (int w = 0; w < 16; w++) {
        if (w < wi || size >= K) continue;
        u64 avail = ~inc[w];
        if (w == wi) avail &= (bi == 63) ? 0ULL : (~0ULL << (bi + 1));
        while (avail != 0ULL && size < K) {
            int b = __builtin_ctzll(avail);
            int j = (w << 6) + b;
            sel[w] |= 1ULL << b;
            size++;
            score += ssd_s[j];
            last = j;
            const u64* rj = ioub + (size_t)j * 16;
            #pragma unroll
            for (int w2 = 0; w2 < 16; w2++) inc[w2] |= rj[w2];
            avail &= ~inc[w];          // row j's own bits clear b et al.
            avail &= ~(1ULL << b);     // safety
        }
    }
    int rec = (size == K) && (last < NB - 1);
    recsc[i] = rec ? score : -1e300;
    #pragma unroll
    for (int w = 0; w < 16; w++) recsel[(size_t)i * 16 + w] = sel[w];
    __threadfence();               // device-scope release of recsc/recsel
    if (t == 0) lastflag = (atomicAdd(ctr, 1) == (int)gridDim.x - 1);
    __syncthreads();
    if (!lastflag) return;
    __threadfence();               // acquire side: see all blocks' writes
    // final: max recorded score, ties -> LAST index (last-argmax rule)
    double bs = -1e301; int bidx = 0;
    for (int m = 0; m < 16; m++) {
        int k = t * 16 + m;        // increasing k; >= keeps the last
        double v = recsc[k];
        if (v >= bs) { bs = v; bidx = k; }
    }
    #pragma unroll
    for (int off = 32; off > 0; off >>= 1) {
        double ob = __shfl_down(bs, off);
        int oi = __shfl_down(bidx, off);
        if (ob > bs || (ob == bs && oi > bidx)) { bs = ob; bidx = oi; }
    }
    bs = __shfl(bs, 0);
    bidx = __shfl(bidx, 0);
    int any = bs > -1e299;
    for (int k = t; k < NB; k += 64) {
        float v = 0.0f;
        if (any && ((recsel[(size_t)bidx * 16 + (k >> 6)] >> (k & 63)) & 1ULL))
            v = (float)ssd_s[k];
        out[k] = v;
    }
}

// ---------------- host entry ------------------------------------------------

extern "C" void kernel_launch(void* const* d_in, const int* in_sizes, int n_in,
                              void* d_out, int out_size, void* d_ws, size_t ws_size,
                              hipStream_t stream) {
    const float* bbox  = (const float*)d_in[0];
    const float* obj   = (const float*)d_in[1];
    const float* probs = (const float*)d_in[2];
    const int*   counts = (const int*)d_in[3];
    float* out = (float*)d_out;

    char* w = (char*)d_ws;
    int4*   coords  = (int4*)(w + OFF_COORDS);
    int4*   rowdesc = (int4*)(w + OFF_RD);
    double* part    = (double*)(w + OFF_PART);
    double* sc64    = (double*)(w + OFF_SC64);
    int*    order   = (int*)(w + OFF_ORDER);
    int*    ctr     = (int*)(w + OFF_CTR);
    u64*    ioub    = (u64*)(w + OFF_IOU);
    double* recsc   = (double*)(w + OFF_RECSC);
    u64*    recsel  = (u64*)(w + OFF_RECSEL);
    float*  Cc      = (float*)(w + OFF_CC);

    k_setup<<<1, 1024, 0, stream>>>(bbox, coords, rowdesc, ctr);
    k_stage<<<(NCHUNK * WW / 4) / 256, 256, 0, stream>>>(probs, rowdesc, part, Cc);
    k_chunkscan<<<WW / 256, 256, 0, stream>>>(part);
    k_boxsum<<<NB, 64, 0, stream>>>(coords, obj, rowdesc, Cc, part, sc64);
    k_rank<<<NB / 128, 128, 0, stream>>>(sc64, order);
    k_iou<<<(NB * NB) / 256, 256, 0, stream>>>(order, bbox, ioub);
    k_group<<<NB / 64, 64, 0, stream>>>(ioub, order, sc64, counts, recsc, recsel,
                                        ctr, out);
}